// Round 9
// baseline (375.821 us; speedup 1.0000x reference)
//
#include <hip/hip_runtime.h>

// GATv2 GNN classifier.
// R9: full pipeline moved bf16 -> fp16. Edge kernel uses packed-fp16 VALU ops
// (pk_add/pk_max/pk_mul) + v_dot2_f32_f16 for logits + packed-fp16 online
// accumulator -> ~2x fewer VALU instructions (R8 showed VALU-bound edge
// phase). GEMMs use mfma_f32_16x16x32_f16 (same rate as bf16, more mantissa).

typedef _Float16 half_t;
typedef _Float16 h2    __attribute__((ext_vector_type(2)));
typedef _Float16 f16x8 __attribute__((ext_vector_type(8)));
typedef float    f32x4 __attribute__((ext_vector_type(4)));

#define SORT_BLOCKS 64
#define SCAN_BLOCKS 256

#if __has_builtin(__builtin_amdgcn_fdot2)
#define FDOT2(a, b, c) __builtin_amdgcn_fdot2((a), (b), (c), false)
#else
#define FDOT2(a, b, c) ((c) + (float)(a)[0] * (float)(b)[0] + (float)(a)[1] * (float)(b)[1])
#endif

// ---------------- fp32 -> fp16 elementwise convert ------------------------
__global__ void cvt_kernel(const float* __restrict__ in,
                           half_t* __restrict__ out, int n)
{
    int i = (blockIdx.x * blockDim.x + threadIdx.x) * 4;
    if (i >= n) return;
    float4 v = *reinterpret_cast<const float4*>(in + i);
    half_t o[4] = {(half_t)v.x, (half_t)v.y, (half_t)v.z, (half_t)v.w};
    *reinterpret_cast<uint2*>(out + i) = *reinterpret_cast<const uint2*>(o);
}

// ---------------- all six W [K][No] fp32 -> Wt [No][K] fp16, one launch ----
__global__ void cvt_wt_all_kernel(
    const float* __restrict__ Wl1, const float* __restrict__ Wr1, half_t* __restrict__ T1l, half_t* __restrict__ T1r,
    const float* __restrict__ Wl2, const float* __restrict__ Wr2, half_t* __restrict__ T2l, half_t* __restrict__ T2r,
    const float* __restrict__ Wl3, const float* __restrict__ Wr3, half_t* __restrict__ T3l, half_t* __restrict__ T3r)
{
    int id = blockIdx.x * blockDim.x + threadIdx.x;
    const float* W; half_t* T; int K, No, idx;
    if (id < 2 * 32768) {            // layer1: 128x256
        K = 128; No = 256; idx = id & 32767;
        W = (id < 32768) ? Wl1 : Wr1; T = (id < 32768) ? T1l : T1r;
    } else if (id < 2 * 32768 + 2 * 32768) {  // layer2: 256x128
        int v = id - 65536; K = 256; No = 128; idx = v & 32767;
        W = (v < 32768) ? Wl2 : Wr2; T = (v < 32768) ? T2l : T2r;
    } else {                          // layer3: 128x64
        int v = id - 131072; if (v >= 2 * 8192) return;
        K = 128; No = 64; idx = v & 8191;
        W = (v < 8192) ? Wl3 : Wr3; T = (v < 8192) ? T3l : T3r;
    }
    int n = idx / K, k = idx - n * K;
    T[idx] = (half_t)W[(size_t)k * No + n];
}

// ---------------- A-resident slab GEMM (fp16 MFMA) -------------------------
// Block owns 64 A-rows; outputs head-major fp16 [h][M][64], coalesced.
template <int K, int NY>
__global__ __launch_bounds__(256) void gemm_slab(
    const half_t* __restrict__ A,     // [M][K] fp16
    const half_t* __restrict__ W0, const half_t* __restrict__ W1,
    const float* __restrict__ bias0, const float* __restrict__ bias1,
    half_t* __restrict__ OutL, half_t* __restrict__ OutR,
    int M)
{
    constexpr int CPR = K / 8;                 // 16B chunks per A row
    __shared__ __align__(16) char As[64 * K * 2];
    __shared__ __align__(16) char Bs[64 * 128 * 2];   // W k-half stage / C stage

    const int t = threadIdx.x;
    const int lane = t & 63;
    const int wid = t >> 6;
    const int row0 = blockIdx.x * 64;

    #pragma unroll
    for (int i = 0; i < (64 * CPR) / 256; ++i) {
        int c16 = i * 256 + t;
        int r = c16 / CPR, j = c16 % CPR;
        int gr = row0 + r; if (gr > M - 1) gr = M - 1;
        uint4 v = *reinterpret_cast<const uint4*>(A + (size_t)gr * K + j * 8);
        *reinterpret_cast<uint4*>(As + r * (2 * K) + ((j ^ (r & 7)) << 4)) = v;
    }

    const int ra = wid * 16 + (lane & 15);
    const int rowA_byte = ra * (2 * K);

    for (int z = 0; z < 2; ++z) {
        const half_t* Wt = z ? W1 : W0;   // [NY*64][K]
        const float* bias = z ? bias1 : bias0;
        half_t* Out = z ? OutR : OutL;
        for (int y = 0; y < NY; ++y) {
            f32x4 acc[4];
            #pragma unroll
            for (int j = 0; j < 4; ++j) acc[j] = (f32x4){0.f, 0.f, 0.f, 0.f};

            #pragma unroll
            for (int kh = 0; kh < K / 128; ++kh) {
                __syncthreads();
                #pragma unroll
                for (int i = 0; i < 4; ++i) {   // stage W tile 64x128 fp16
                    int c16 = i * 256 + t;
                    int n = c16 >> 4, j = c16 & 15;
                    uint4 v = *reinterpret_cast<const uint4*>(
                        Wt + (size_t)(y * 64 + n) * K + kh * 128 + j * 8);
                    *reinterpret_cast<uint4*>(Bs + n * 256 + ((j ^ (n & 7)) << 4)) = v;
                }
                __syncthreads();
                #pragma unroll
                for (int ks = 0; ks < 4; ++ks) {
                    int chA = kh * 16 + ks * 4 + (lane >> 4);
                    f16x8 a = *reinterpret_cast<const f16x8*>(
                        As + rowA_byte + ((chA ^ (ra & 7)) << 4));
                    #pragma unroll
                    for (int j = 0; j < 4; ++j) {
                        int nb = j * 16 + (lane & 15);
                        int chB = ks * 4 + (lane >> 4);
                        f16x8 b = *reinterpret_cast<const f16x8*>(
                            Bs + nb * 256 + ((chB ^ (nb & 7)) << 4));
                        acc[j] = __builtin_amdgcn_mfma_f32_16x16x32_f16(a, b, acc[j], 0, 0, 0);
                    }
                }
            }
            __syncthreads();            // all Bs reads done
            #pragma unroll
            for (int j = 0; j < 4; ++j) {
                float bb = bias[y * 64 + j * 16 + (lane & 15)];
                #pragma unroll
                for (int q = 0; q < 4; ++q) {
                    int r = wid * 16 + (lane >> 4) * 4 + q;
                    int c = j * 16 + (lane & 15);
                    *reinterpret_cast<half_t*>(Bs + r * 128 + c * 2)
                        = (half_t)(acc[j][q] + bb);
                }
            }
            __syncthreads();
            {
                int r = t >> 2, ch = t & 3;
                int gr = row0 + r;
                if (gr < M) {
                    const uint4* src = reinterpret_cast<const uint4*>(Bs + r * 128 + ch * 32);
                    uint4 v0 = src[0], v1 = src[1];
                    uint4* dst = reinterpret_cast<uint4*>(
                        Out + ((size_t)y * M + gr) * 64 + ch * 16);
                    dst[0] = v0; dst[1] = v1;
                }
            }
        }
    }
}

// ---------------- CSR build ------------------------------------------------
__global__ void hist_kernel(const int* __restrict__ ei, int E, int Etot,
                            int* __restrict__ deg)
{
    int i = blockIdx.x * blockDim.x + threadIdx.x;
    if (i >= Etot) return;
    int d = (i < E) ? ei[E + i] : (i - E);
    atomicAdd(&deg[d], 1);
}

// ---- 3-phase coalesced scan of deg[0..N) -> rowptr/cursor ----------------
__global__ __launch_bounds__(256) void scan1_kernel(
    const int* __restrict__ deg, int* __restrict__ blockSums, int N)
{
    __shared__ int red[256];
    const int b = blockIdx.x, t = threadIdx.x;
    const int chunk = (N + SCAN_BLOCKS - 1) / SCAN_BLOCKS;
    const int lo = b * chunk;
    const int hi = (lo + chunk < N) ? lo + chunk : N;
    int s = 0;
    for (int i = lo + t; i < hi; i += 256) s += deg[i];
    red[t] = s;
    __syncthreads();
    #pragma unroll
    for (int off = 128; off > 0; off >>= 1) {
        if (t < off) red[t] += red[t + off];
        __syncthreads();
    }
    if (t == 0) blockSums[b] = red[0];
}

__global__ __launch_bounds__(256) void scan2_kernel(
    const int* __restrict__ blockSums, int* __restrict__ blockBase,
    int* __restrict__ rowptr, int N)
{
    __shared__ int tmp[256];
    const int t = threadIdx.x;
    int v = blockSums[t];
    tmp[t] = v;
    __syncthreads();
    for (int off = 1; off < 256; off <<= 1) {
        int u = (t >= off) ? tmp[t - off] : 0;
        __syncthreads();
        tmp[t] += u;
        __syncthreads();
    }
    blockBase[t] = tmp[t] - v;        // exclusive
    if (t == 255) rowptr[N] = tmp[255];
}

__global__ __launch_bounds__(256) void scan3_kernel(
    const int* __restrict__ deg, const int* __restrict__ blockBase,
    int* __restrict__ rowptr, int* __restrict__ cursor, int N)
{
    __shared__ int tmp[256];
    __shared__ int carry;
    const int b = blockIdx.x, t = threadIdx.x;
    const int chunk = (N + SCAN_BLOCKS - 1) / SCAN_BLOCKS;
    const int lo = b * chunk;
    const int hi = (lo + chunk < N) ? lo + chunk : N;
    if (t == 0) carry = blockBase[b];
    __syncthreads();
    for (int j = lo; j < hi; j += 256) {
        int i = j + t;
        int v = (i < hi) ? deg[i] : 0;
        tmp[t] = v;
        __syncthreads();
        for (int off = 1; off < 256; off <<= 1) {
            int u = (t >= off) ? tmp[t - off] : 0;
            __syncthreads();
            tmp[t] += u;
            __syncthreads();
        }
        int excl = carry + tmp[t] - v;
        if (i < hi) { rowptr[i] = excl; cursor[i] = excl; }
        __syncthreads();
        if (t == 255) carry += tmp[255];
        __syncthreads();
    }
}

__global__ void scatter_kernel(const int* __restrict__ ei, int E, int Etot,
                               int* __restrict__ cursor, int* __restrict__ ssrc)
{
    int i = blockIdx.x * blockDim.x + threadIdx.x;
    if (i >= Etot) return;
    int d, s;
    if (i < E) { s = ei[i]; d = ei[E + i]; }
    else       { s = i - E; d = s; }
    int pos = atomicAdd(&cursor[d], 1);
    ssrc[pos] = s;
}

// ---------------- degree sort (DESCENDING), contention-free ---------------
__global__ __launch_bounds__(256) void dhist2_kernel(
    const int* __restrict__ rowptr, int* __restrict__ blockHist, int N)
{
    __shared__ int lh[256];
    lh[threadIdx.x] = 0;
    __syncthreads();
    const int chunk = (N + SORT_BLOCKS - 1) / SORT_BLOCKS;
    const int lo = blockIdx.x * chunk;
    const int hi = (lo + chunk < N) ? lo + chunk : N;
    for (int d = lo + threadIdx.x; d < hi; d += 256) {
        int deg = rowptr[d + 1] - rowptr[d];
        atomicAdd(&lh[deg > 255 ? 255 : deg], 1);
    }
    __syncthreads();
    blockHist[blockIdx.x * 256 + threadIdx.x] = lh[threadIdx.x];
}

__global__ __launch_bounds__(256) void dscan2_kernel(
    const int* __restrict__ blockHist, int* __restrict__ blockOff)
{
    const int t = threadIdx.x;          // t = bin
    int total = 0;
    for (int b = 0; b < SORT_BLOCKS; ++b) total += blockHist[b * 256 + t];
    __shared__ int tmp[256];
    tmp[t] = total;
    __syncthreads();
    for (int off = 1; off < 256; off <<= 1) {
        int v = (t >= off) ? tmp[t - off] : 0;
        __syncthreads();
        tmp[t] += v;
        __syncthreads();
    }
    int grand = tmp[255];
    int start = grand - tmp[t];       // descending
    for (int b = 0; b < SORT_BLOCKS; ++b) {
        blockOff[b * 256 + t] = start;
        start += blockHist[b * 256 + t];
    }
}

__global__ __launch_bounds__(256) void dscatter2_kernel(
    const int* __restrict__ rowptr, const int* __restrict__ blockOff,
    int* __restrict__ dperm, int N)
{
    __shared__ int cur[256];
    cur[threadIdx.x] = blockOff[blockIdx.x * 256 + threadIdx.x];
    __syncthreads();
    const int chunk = (N + SORT_BLOCKS - 1) / SORT_BLOCKS;
    const int lo = blockIdx.x * chunk;
    const int hi = (lo + chunk < N) ? lo + chunk : N;
    for (int d = lo + threadIdx.x; d < hi; d += 256) {
        int deg = rowptr[d + 1] - rowptr[d];
        int pos = atomicAdd(&cur[deg > 255 ? 255 : deg], 1);
        dperm[pos] = d;
    }
}

// ---------------- fused edge kernel: 4-lane group per (dst, head) ---------
// Head-major fp16: xl/xr [h][N][64]. Packed-fp16 math; logits via fdot2.
template <int H, bool OUT_F32, bool OUT_F16>
__global__ __launch_bounds__(256) void gat_fused4(
    const int* __restrict__ rowptr, const int* __restrict__ ssrc,
    const int* __restrict__ dperm,
    const half_t* __restrict__ xl, const half_t* __restrict__ xr,
    const float* __restrict__ att, const float* __restrict__ bias,
    float* __restrict__ outf, half_t* __restrict__ outb, int N)
{
    const int gid = blockIdx.x * 64 + (threadIdx.x >> 2);
    const int sub = threadIdx.x & 3;
    if (gid >= N * H) return;
    const int h  = gid / N;               // head-major ordering
    const int di = gid - h * N;
    const int d  = dperm[di];
    const int HC = H * 64;
    const int so = sub * 16;

    const half_t* xlh = xl + (size_t)h * N * 64;
    const h2 c02 = {(half_t)0.2f, (half_t)0.2f};

    h2 xrv[8], attv[8], acc[8];
    {
        const half_t* pr = xr + ((size_t)h * N + d) * 64 + so;
        uint4 rb[2];
        rb[0] = *reinterpret_cast<const uint4*>(pr);
        rb[1] = *reinterpret_cast<const uint4*>(pr + 8);
        const h2* rp = reinterpret_cast<const h2*>(rb);
        const float* pa = att + h * 64 + so;
        #pragma unroll
        for (int k = 0; k < 8; ++k) {
            xrv[k] = rp[k];
            attv[k] = (h2){(half_t)pa[2 * k], (half_t)pa[2 * k + 1]};
            acc[k] = (h2){(half_t)0.f, (half_t)0.f};
        }
    }
    float M = -3.0e38f, S = 0.f;

    const int begin = rowptr[d], end = rowptr[d + 1];
    uint4 cbuf[2];
    {
        const half_t* pl = xlh + (size_t)ssrc[begin] * 64 + so;
        cbuf[0] = *reinterpret_cast<const uint4*>(pl);
        cbuf[1] = *reinterpret_cast<const uint4*>(pl + 8);
    }
    for (int e = begin; e < end; ++e) {
        uint4 nbuf[2];
        const bool more = (e + 1 < end);
        if (more) {
            const half_t* pl = xlh + (size_t)ssrc[e + 1] * 64 + so;
            nbuf[0] = *reinterpret_cast<const uint4*>(pl);
            nbuf[1] = *reinterpret_cast<const uint4*>(pl + 8);
        }
        const h2* cur = reinterpret_cast<const h2*>(cbuf);
        float p = 0.f;
        #pragma unroll
        for (int k = 0; k < 8; ++k) {
            h2 m = cur[k] + xrv[k];
            h2 v = __builtin_elementwise_max(m, m * c02);   // leaky_relu 0.2
            p = FDOT2(v, attv[k], p);
        }
        p += __shfl_xor(p, 1);
        p += __shfl_xor(p, 2);
        float nM = fmaxf(M, p);
        float scale = __expf(M - nM);
        float w = __expf(p - nM);
        S = fmaf(S, scale, w);
        h2 s2 = {(half_t)scale, (half_t)scale};
        h2 w2 = {(half_t)w, (half_t)w};
        #pragma unroll
        for (int k = 0; k < 8; ++k) acc[k] = acc[k] * s2 + cur[k] * w2;
        M = nM;
        if (more) { cbuf[0] = nbuf[0]; cbuf[1] = nbuf[1]; }
    }
    float inv = 1.f / S;
    const float* pb = bias + h * 64 + so;
    float res[16];
    #pragma unroll
    for (int k = 0; k < 8; ++k) {
        float v0 = fmaf((float)acc[k][0], inv, pb[2 * k]);
        float v1 = fmaf((float)acc[k][1], inv, pb[2 * k + 1]);
        res[2 * k]     = v0 > 0.f ? v0 : 0.f;
        res[2 * k + 1] = v1 > 0.f ? v1 : 0.f;
    }
    size_t ob = (size_t)d * HC + h * 64 + so;    // node-major output (GEMM A)
    if (OUT_F32) {
        #pragma unroll
        for (int k = 0; k < 16; k += 4) {
            float4 v = {res[k], res[k+1], res[k+2], res[k+3]};
            *reinterpret_cast<float4*>(outf + ob + k) = v;
        }
    }
    if (OUT_F16) {
        half_t o[16];
        #pragma unroll
        for (int k = 0; k < 16; ++k) o[k] = (half_t)res[k];
        const uint4* ov = reinterpret_cast<const uint4*>(o);
        *reinterpret_cast<uint4*>(outb + ob) = ov[0];
        *reinterpret_cast<uint4*>(outb + ob + 8) = ov[1];
    }
}

// ---------------- segmented pool (batch sorted) + counts ------------------
__global__ __launch_bounds__(256) void pool_kernel2(
    const float* __restrict__ h3, const int* __restrict__ batch,
    float* __restrict__ sums, float* __restrict__ counts, int N)
{
    const int wave = blockIdx.x * 4 + (threadIdx.x >> 6);
    const int lane = threadIdx.x & 63;
    const int n0 = wave * 64;
    if (n0 >= N) return;
    const int n1 = (n0 + 64 < N) ? n0 + 64 : N;
    float s = 0.f, cnt = 0.f;
    int g = batch[n0];
    for (int n = n0; n < n1; ++n) {
        int gn = batch[n];
        if (gn != g) {
            atomicAdd(&sums[g * 64 + lane], s);
            if (lane == 0) atomicAdd(&counts[g], cnt);
            s = 0.f; cnt = 0.f; g = gn;
        }
        s += h3[(size_t)n * 64 + lane];
        cnt += 1.f;
    }
    atomicAdd(&sums[g * 64 + lane], s);
    if (lane == 0) atomicAdd(&counts[g], cnt);
}

// ---------------- MLP ------------------------------------------------------
__global__ __launch_bounds__(64) void mlp_kernel(
    const float* __restrict__ sums, const float* __restrict__ counts,
    const float* __restrict__ Wm1, const float* __restrict__ bm1,
    const float* __restrict__ Wm2, const float* __restrict__ bm2,
    float* __restrict__ out)
{
    int g = blockIdx.x;
    int t = threadIdx.x;
    __shared__ float pooled[64];
    __shared__ float hidden[32];
    float cnt = counts[g];
    cnt = cnt > 1.f ? cnt : 1.f;
    pooled[t] = sums[g * 64 + t] / cnt;
    __syncthreads();
    if (t < 32) {
        float a = bm1[t];
        #pragma unroll
        for (int k = 0; k < 64; ++k) a = fmaf(pooled[k], Wm1[k * 32 + t], a);
        hidden[t] = a > 0.f ? a : 0.f;
    }
    __syncthreads();
    if (t < 2) {
        float a = bm2[t];
        #pragma unroll
        for (int j = 0; j < 32; ++j) a = fmaf(hidden[j], Wm2[j * 2 + t], a);
        out[g * 2 + t] = a;
    }
}

// ---------------- layer driver ---------------------------------------------
static void run_layer(const half_t* Xb, int K, int H,
                      const float* bl, const float* br,
                      const float* att, const float* bias_out,
                      const half_t* Wtl, const half_t* Wtr,
                      const int* rowptr, const int* ssrc, const int* dperm, int N,
                      half_t* xl, half_t* xr,
                      float* houtf, half_t* houtb,
                      hipStream_t stream)
{
    int gblocks = (N + 63) / 64;
    if (K == 128 && H == 4)
        gemm_slab<128, 4><<<gblocks, 256, 0, stream>>>(Xb, Wtl, Wtr, bl, br, xl, xr, N);
    else if (K == 256)
        gemm_slab<256, 2><<<gblocks, 256, 0, stream>>>(Xb, Wtl, Wtr, bl, br, xl, xr, N);
    else
        gemm_slab<128, 1><<<gblocks, 256, 0, stream>>>(Xb, Wtl, Wtr, bl, br, xl, xr, N);

    int ngroups = N * H;
    int blocks = (ngroups + 63) / 64;
    if (H == 4)
        gat_fused4<4, false, true><<<blocks, 256, 0, stream>>>(
            rowptr, ssrc, dperm, xl, xr, att, bias_out, houtf, houtb, N);
    else if (H == 2)
        gat_fused4<2, false, true><<<blocks, 256, 0, stream>>>(
            rowptr, ssrc, dperm, xl, xr, att, bias_out, houtf, houtb, N);
    else
        gat_fused4<1, true, false><<<blocks, 256, 0, stream>>>(
            rowptr, ssrc, dperm, xl, xr, att, bias_out, houtf, houtb, N);
}

extern "C" void kernel_launch(void* const* d_in, const int* in_sizes, int n_in,
                              void* d_out, int out_size, void* d_ws, size_t ws_size,
                              hipStream_t stream)
{
    const float* x    = (const float*)d_in[0];
    const int*   ei   = (const int*)d_in[1];
    const int*   batch= (const int*)d_in[2];
    const float* Wl1 = (const float*)d_in[3];
    const float* bl1 = (const float*)d_in[4];
    const float* Wr1 = (const float*)d_in[5];
    const float* br1 = (const float*)d_in[6];
    const float* att1= (const float*)d_in[7];
    const float* b1  = (const float*)d_in[8];
    const float* Wl2 = (const float*)d_in[9];
    const float* bl2 = (const float*)d_in[10];
    const float* Wr2 = (const float*)d_in[11];
    const float* br2 = (const float*)d_in[12];
    const float* att2= (const float*)d_in[13];
    const float* b2  = (const float*)d_in[14];
    const float* Wl3 = (const float*)d_in[15];
    const float* bl3 = (const float*)d_in[16];
    const float* Wr3 = (const float*)d_in[17];
    const float* br3 = (const float*)d_in[18];
    const float* att3= (const float*)d_in[19];
    const float* b3  = (const float*)d_in[20];
    const float* Wm1 = (const float*)d_in[21];
    const float* bm1 = (const float*)d_in[22];
    const float* Wm2 = (const float*)d_in[23];
    const float* bm2 = (const float*)d_in[24];

    const int N    = in_sizes[2];          // 50000
    const int E    = in_sizes[1] / 2;      // 800000
    const int Etot = E + N;                // + self loops
    const int K1   = in_sizes[0] / N;      // 128

    // workspace layout
    char* wsb = (char*)d_ws;
    size_t o = 0;
    auto alloc = [&](size_t bytes) { char* p = wsb + o; o += (bytes + 255) & ~(size_t)255; return p; };
    half_t* xl    = (half_t*)alloc((size_t)N * 256 * 2);
    half_t* xr    = (half_t*)alloc((size_t)N * 256 * 2);
    half_t* xb    = (half_t*)alloc((size_t)N * K1 * 2);
    half_t* h1b   = (half_t*)alloc((size_t)N * 256 * 2);
    half_t* h2b   = (half_t*)alloc((size_t)N * 128 * 2);
    float*  h3f   = (float*)alloc((size_t)N * 64 * 4);
    int*   deg    = (int*)alloc((size_t)N * 4);
    int*   rowptr = (int*)alloc((size_t)(N + 1) * 4);
    int*   cursor = (int*)alloc((size_t)N * 4);
    int*   ssrc   = (int*)alloc((size_t)Etot * 4);
    int*   dperm  = (int*)alloc((size_t)N * 4);
    int*   blockHist = (int*)alloc((size_t)SORT_BLOCKS * 256 * 4);
    int*   blockOff  = (int*)alloc((size_t)SORT_BLOCKS * 256 * 4);
    int*   blockSums = (int*)alloc((size_t)SCAN_BLOCKS * 4);
    int*   blockBase = (int*)alloc((size_t)SCAN_BLOCKS * 4);
    half_t* Wt1l = (half_t*)alloc(128 * 256 * 2);
    half_t* Wt1r = (half_t*)alloc(128 * 256 * 2);
    half_t* Wt2l = (half_t*)alloc(256 * 128 * 2);
    half_t* Wt2r = (half_t*)alloc(256 * 128 * 2);
    half_t* Wt3l = (half_t*)alloc(128 * 64 * 2);
    half_t* Wt3r = (half_t*)alloc(128 * 64 * 2);
    float* sums   = (float*)alloc(64 * 64 * 4);
    float* counts = (float*)alloc(64 * 4);
    (void)ws_size; (void)n_in; (void)out_size;

    // ---- CSR build + degree sort (shared by all 3 layers) ----
    hipMemsetAsync(deg, 0, (size_t)N * 4, stream);
    hist_kernel<<<(Etot + 255) / 256, 256, 0, stream>>>(ei, E, Etot, deg);
    scan1_kernel<<<SCAN_BLOCKS, 256, 0, stream>>>(deg, blockSums, N);
    scan2_kernel<<<1, 256, 0, stream>>>(blockSums, blockBase, rowptr, N);
    scan3_kernel<<<SCAN_BLOCKS, 256, 0, stream>>>(deg, blockBase, rowptr, cursor, N);
    scatter_kernel<<<(Etot + 255) / 256, 256, 0, stream>>>(ei, E, Etot, cursor, ssrc);
    dhist2_kernel<<<SORT_BLOCKS, 256, 0, stream>>>(rowptr, blockHist, N);
    dscan2_kernel<<<1, 256, 0, stream>>>(blockHist, blockOff);
    dscatter2_kernel<<<SORT_BLOCKS, 256, 0, stream>>>(rowptr, blockOff, dperm, N);

    // ---- convert input x + all weights to fp16 ----
    cvt_kernel<<<((N * K1) / 4 + 255) / 256, 256, 0, stream>>>(x, xb, N * K1);
    cvt_wt_all_kernel<<<(147456 + 255) / 256, 256, 0, stream>>>(
        Wl1, Wr1, Wt1l, Wt1r, Wl2, Wr2, Wt2l, Wt2r, Wl3, Wr3, Wt3l, Wt3r);

    // ---- layers ----
    run_layer(xb, K1, 4, bl1, br1, att1, b1, Wt1l, Wt1r,
              rowptr, ssrc, dperm, N, xl, xr, nullptr, h1b, stream);
    run_layer(h1b, 256, 2, bl2, br2, att2, b2, Wt2l, Wt2r,
              rowptr, ssrc, dperm, N, xl, xr, nullptr, h2b, stream);
    run_layer(h2b, 128, 1, bl3, br3, att3, b3, Wt3l, Wt3r,
              rowptr, ssrc, dperm, N, xl, xr, h3f, nullptr, stream);

    // ---- pool + MLP ----
    hipMemsetAsync(sums, 0, 64 * 64 * 4, stream);
    hipMemsetAsync(counts, 0, 64 * 4, stream);
    {
        int waves = (N + 63) / 64;
        pool_kernel2<<<(waves + 3) / 4, 256, 0, stream>>>(h3f, batch, sums, counts, N);
    }
    mlp_kernel<<<64, 64, 0, stream>>>(sums, counts, Wm1, bm1, Wm2, bm2, (float*)d_out);
}

// Round 10
// 371.784 us; speedup vs baseline: 1.0109x; 1.0109x over previous
//
#include <hip/hip_runtime.h>

// GATv2 GNN classifier.
// R10: depth-2 software pipeline in the edge kernel (gathers for e+1 AND e+2
// in flight while computing e). R9 post-mortem: fp16 halved VALU but exposed
// gather latency (VALUBusy 65->37%, dur up); restore hiding via deeper MLP.
// Rest identical to R9 (fp16 MFMA slab GEMMs, packed-fp16 edge math).

typedef _Float16 half_t;
typedef _Float16 h2    __attribute__((ext_vector_type(2)));
typedef _Float16 f16x8 __attribute__((ext_vector_type(8)));
typedef float    f32x4 __attribute__((ext_vector_type(4)));

#define SORT_BLOCKS 64
#define SCAN_BLOCKS 256

#if __has_builtin(__builtin_amdgcn_fdot2)
#define FDOT2(a, b, c) __builtin_amdgcn_fdot2((a), (b), (c), false)
#else
#define FDOT2(a, b, c) ((c) + (float)(a)[0] * (float)(b)[0] + (float)(a)[1] * (float)(b)[1])
#endif

// ---------------- fp32 -> fp16 elementwise convert ------------------------
__global__ void cvt_kernel(const float* __restrict__ in,
                           half_t* __restrict__ out, int n)
{
    int i = (blockIdx.x * blockDim.x + threadIdx.x) * 4;
    if (i >= n) return;
    float4 v = *reinterpret_cast<const float4*>(in + i);
    half_t o[4] = {(half_t)v.x, (half_t)v.y, (half_t)v.z, (half_t)v.w};
    *reinterpret_cast<uint2*>(out + i) = *reinterpret_cast<const uint2*>(o);
}

// ---------------- all six W [K][No] fp32 -> Wt [No][K] fp16, one launch ----
__global__ void cvt_wt_all_kernel(
    const float* __restrict__ Wl1, const float* __restrict__ Wr1, half_t* __restrict__ T1l, half_t* __restrict__ T1r,
    const float* __restrict__ Wl2, const float* __restrict__ Wr2, half_t* __restrict__ T2l, half_t* __restrict__ T2r,
    const float* __restrict__ Wl3, const float* __restrict__ Wr3, half_t* __restrict__ T3l, half_t* __restrict__ T3r)
{
    int id = blockIdx.x * blockDim.x + threadIdx.x;
    const float* W; half_t* T; int K, No, idx;
    if (id < 2 * 32768) {            // layer1: 128x256
        K = 128; No = 256; idx = id & 32767;
        W = (id < 32768) ? Wl1 : Wr1; T = (id < 32768) ? T1l : T1r;
    } else if (id < 2 * 32768 + 2 * 32768) {  // layer2: 256x128
        int v = id - 65536; K = 256; No = 128; idx = v & 32767;
        W = (v < 32768) ? Wl2 : Wr2; T = (v < 32768) ? T2l : T2r;
    } else {                          // layer3: 128x64
        int v = id - 131072; if (v >= 2 * 8192) return;
        K = 128; No = 64; idx = v & 8191;
        W = (v < 8192) ? Wl3 : Wr3; T = (v < 8192) ? T3l : T3r;
    }
    int n = idx / K, k = idx - n * K;
    T[idx] = (half_t)W[(size_t)k * No + n];
}

// ---------------- A-resident slab GEMM (fp16 MFMA) -------------------------
template <int K, int NY>
__global__ __launch_bounds__(256) void gemm_slab(
    const half_t* __restrict__ A,     // [M][K] fp16
    const half_t* __restrict__ W0, const half_t* __restrict__ W1,
    const float* __restrict__ bias0, const float* __restrict__ bias1,
    half_t* __restrict__ OutL, half_t* __restrict__ OutR,
    int M)
{
    constexpr int CPR = K / 8;                 // 16B chunks per A row
    __shared__ __align__(16) char As[64 * K * 2];
    __shared__ __align__(16) char Bs[64 * 128 * 2];   // W k-half stage / C stage

    const int t = threadIdx.x;
    const int lane = t & 63;
    const int wid = t >> 6;
    const int row0 = blockIdx.x * 64;

    #pragma unroll
    for (int i = 0; i < (64 * CPR) / 256; ++i) {
        int c16 = i * 256 + t;
        int r = c16 / CPR, j = c16 % CPR;
        int gr = row0 + r; if (gr > M - 1) gr = M - 1;
        uint4 v = *reinterpret_cast<const uint4*>(A + (size_t)gr * K + j * 8);
        *reinterpret_cast<uint4*>(As + r * (2 * K) + ((j ^ (r & 7)) << 4)) = v;
    }

    const int ra = wid * 16 + (lane & 15);
    const int rowA_byte = ra * (2 * K);

    for (int z = 0; z < 2; ++z) {
        const half_t* Wt = z ? W1 : W0;   // [NY*64][K]
        const float* bias = z ? bias1 : bias0;
        half_t* Out = z ? OutR : OutL;
        for (int y = 0; y < NY; ++y) {
            f32x4 acc[4];
            #pragma unroll
            for (int j = 0; j < 4; ++j) acc[j] = (f32x4){0.f, 0.f, 0.f, 0.f};

            #pragma unroll
            for (int kh = 0; kh < K / 128; ++kh) {
                __syncthreads();
                #pragma unroll
                for (int i = 0; i < 4; ++i) {   // stage W tile 64x128 fp16
                    int c16 = i * 256 + t;
                    int n = c16 >> 4, j = c16 & 15;
                    uint4 v = *reinterpret_cast<const uint4*>(
                        Wt + (size_t)(y * 64 + n) * K + kh * 128 + j * 8);
                    *reinterpret_cast<uint4*>(Bs + n * 256 + ((j ^ (n & 7)) << 4)) = v;
                }
                __syncthreads();
                #pragma unroll
                for (int ks = 0; ks < 4; ++ks) {
                    int chA = kh * 16 + ks * 4 + (lane >> 4);
                    f16x8 a = *reinterpret_cast<const f16x8*>(
                        As + rowA_byte + ((chA ^ (ra & 7)) << 4));
                    #pragma unroll
                    for (int j = 0; j < 4; ++j) {
                        int nb = j * 16 + (lane & 15);
                        int chB = ks * 4 + (lane >> 4);
                        f16x8 b = *reinterpret_cast<const f16x8*>(
                            Bs + nb * 256 + ((chB ^ (nb & 7)) << 4));
                        acc[j] = __builtin_amdgcn_mfma_f32_16x16x32_f16(a, b, acc[j], 0, 0, 0);
                    }
                }
            }
            __syncthreads();            // all Bs reads done
            #pragma unroll
            for (int j = 0; j < 4; ++j) {
                float bb = bias[y * 64 + j * 16 + (lane & 15)];
                #pragma unroll
                for (int q = 0; q < 4; ++q) {
                    int r = wid * 16 + (lane >> 4) * 4 + q;
                    int c = j * 16 + (lane & 15);
                    *reinterpret_cast<half_t*>(Bs + r * 128 + c * 2)
                        = (half_t)(acc[j][q] + bb);
                }
            }
            __syncthreads();
            {
                int r = t >> 2, ch = t & 3;
                int gr = row0 + r;
                if (gr < M) {
                    const uint4* src = reinterpret_cast<const uint4*>(Bs + r * 128 + ch * 32);
                    uint4 v0 = src[0], v1 = src[1];
                    uint4* dst = reinterpret_cast<uint4*>(
                        Out + ((size_t)y * M + gr) * 64 + ch * 16);
                    dst[0] = v0; dst[1] = v1;
                }
            }
        }
    }
}

// ---------------- CSR build ------------------------------------------------
__global__ void hist_kernel(const int* __restrict__ ei, int E, int Etot,
                            int* __restrict__ deg)
{
    int i = blockIdx.x * blockDim.x + threadIdx.x;
    if (i >= Etot) return;
    int d = (i < E) ? ei[E + i] : (i - E);
    atomicAdd(&deg[d], 1);
}

// ---- 3-phase coalesced scan of deg[0..N) -> rowptr/cursor ----------------
__global__ __launch_bounds__(256) void scan1_kernel(
    const int* __restrict__ deg, int* __restrict__ blockSums, int N)
{
    __shared__ int red[256];
    const int b = blockIdx.x, t = threadIdx.x;
    const int chunk = (N + SCAN_BLOCKS - 1) / SCAN_BLOCKS;
    const int lo = b * chunk;
    const int hi = (lo + chunk < N) ? lo + chunk : N;
    int s = 0;
    for (int i = lo + t; i < hi; i += 256) s += deg[i];
    red[t] = s;
    __syncthreads();
    #pragma unroll
    for (int off = 128; off > 0; off >>= 1) {
        if (t < off) red[t] += red[t + off];
        __syncthreads();
    }
    if (t == 0) blockSums[b] = red[0];
}

__global__ __launch_bounds__(256) void scan2_kernel(
    const int* __restrict__ blockSums, int* __restrict__ blockBase,
    int* __restrict__ rowptr, int N)
{
    __shared__ int tmp[256];
    const int t = threadIdx.x;
    int v = blockSums[t];
    tmp[t] = v;
    __syncthreads();
    for (int off = 1; off < 256; off <<= 1) {
        int u = (t >= off) ? tmp[t - off] : 0;
        __syncthreads();
        tmp[t] += u;
        __syncthreads();
    }
    blockBase[t] = tmp[t] - v;        // exclusive
    if (t == 255) rowptr[N] = tmp[255];
}

__global__ __launch_bounds__(256) void scan3_kernel(
    const int* __restrict__ deg, const int* __restrict__ blockBase,
    int* __restrict__ rowptr, int* __restrict__ cursor, int N)
{
    __shared__ int tmp[256];
    __shared__ int carry;
    const int b = blockIdx.x, t = threadIdx.x;
    const int chunk = (N + SCAN_BLOCKS - 1) / SCAN_BLOCKS;
    const int lo = b * chunk;
    const int hi = (lo + chunk < N) ? lo + chunk : N;
    if (t == 0) carry = blockBase[b];
    __syncthreads();
    for (int j = lo; j < hi; j += 256) {
        int i = j + t;
        int v = (i < hi) ? deg[i] : 0;
        tmp[t] = v;
        __syncthreads();
        for (int off = 1; off < 256; off <<= 1) {
            int u = (t >= off) ? tmp[t - off] : 0;
            __syncthreads();
            tmp[t] += u;
            __syncthreads();
        }
        int excl = carry + tmp[t] - v;
        if (i < hi) { rowptr[i] = excl; cursor[i] = excl; }
        __syncthreads();
        if (t == 255) carry += tmp[255];
        __syncthreads();
    }
}

__global__ void scatter_kernel(const int* __restrict__ ei, int E, int Etot,
                               int* __restrict__ cursor, int* __restrict__ ssrc)
{
    int i = blockIdx.x * blockDim.x + threadIdx.x;
    if (i >= Etot) return;
    int d, s;
    if (i < E) { s = ei[i]; d = ei[E + i]; }
    else       { s = i - E; d = s; }
    int pos = atomicAdd(&cursor[d], 1);
    ssrc[pos] = s;
}

// ---------------- degree sort (DESCENDING), contention-free ---------------
__global__ __launch_bounds__(256) void dhist2_kernel(
    const int* __restrict__ rowptr, int* __restrict__ blockHist, int N)
{
    __shared__ int lh[256];
    lh[threadIdx.x] = 0;
    __syncthreads();
    const int chunk = (N + SORT_BLOCKS - 1) / SORT_BLOCKS;
    const int lo = blockIdx.x * chunk;
    const int hi = (lo + chunk < N) ? lo + chunk : N;
    for (int d = lo + threadIdx.x; d < hi; d += 256) {
        int deg = rowptr[d + 1] - rowptr[d];
        atomicAdd(&lh[deg > 255 ? 255 : deg], 1);
    }
    __syncthreads();
    blockHist[blockIdx.x * 256 + threadIdx.x] = lh[threadIdx.x];
}

__global__ __launch_bounds__(256) void dscan2_kernel(
    const int* __restrict__ blockHist, int* __restrict__ blockOff)
{
    const int t = threadIdx.x;          // t = bin
    int total = 0;
    for (int b = 0; b < SORT_BLOCKS; ++b) total += blockHist[b * 256 + t];
    __shared__ int tmp[256];
    tmp[t] = total;
    __syncthreads();
    for (int off = 1; off < 256; off <<= 1) {
        int v = (t >= off) ? tmp[t - off] : 0;
        __syncthreads();
        tmp[t] += v;
        __syncthreads();
    }
    int grand = tmp[255];
    int start = grand - tmp[t];       // descending
    for (int b = 0; b < SORT_BLOCKS; ++b) {
        blockOff[b * 256 + t] = start;
        start += blockHist[b * 256 + t];
    }
}

__global__ __launch_bounds__(256) void dscatter2_kernel(
    const int* __restrict__ rowptr, const int* __restrict__ blockOff,
    int* __restrict__ dperm, int N)
{
    __shared__ int cur[256];
    cur[threadIdx.x] = blockOff[blockIdx.x * 256 + threadIdx.x];
    __syncthreads();
    const int chunk = (N + SORT_BLOCKS - 1) / SORT_BLOCKS;
    const int lo = blockIdx.x * chunk;
    const int hi = (lo + chunk < N) ? lo + chunk : N;
    for (int d = lo + threadIdx.x; d < hi; d += 256) {
        int deg = rowptr[d + 1] - rowptr[d];
        int pos = atomicAdd(&cur[deg > 255 ? 255 : deg], 1);
        dperm[pos] = d;
    }
}

// ---------------- fused edge kernel: 4-lane group per (dst, head) ---------
// Head-major fp16: xl/xr [h][N][64]. Depth-2 gather pipeline.
template <int H, bool OUT_F32, bool OUT_F16>
__global__ __launch_bounds__(256) void gat_fused4(
    const int* __restrict__ rowptr, const int* __restrict__ ssrc,
    const int* __restrict__ dperm,
    const half_t* __restrict__ xl, const half_t* __restrict__ xr,
    const float* __restrict__ att, const float* __restrict__ bias,
    float* __restrict__ outf, half_t* __restrict__ outb, int N)
{
    const int gid = blockIdx.x * 64 + (threadIdx.x >> 2);
    const int sub = threadIdx.x & 3;
    if (gid >= N * H) return;
    const int h  = gid / N;               // head-major ordering
    const int di = gid - h * N;
    const int d  = dperm[di];
    const int HC = H * 64;
    const int so = sub * 16;

    const half_t* xlh = xl + (size_t)h * N * 64;
    const h2 c02 = {(half_t)0.2f, (half_t)0.2f};

    h2 xrv[8], attv[8], acc[8];
    {
        const half_t* pr = xr + ((size_t)h * N + d) * 64 + so;
        uint4 rb[2];
        rb[0] = *reinterpret_cast<const uint4*>(pr);
        rb[1] = *reinterpret_cast<const uint4*>(pr + 8);
        const h2* rp = reinterpret_cast<const h2*>(rb);
        const float* pa = att + h * 64 + so;
        #pragma unroll
        for (int k = 0; k < 8; ++k) {
            xrv[k] = rp[k];
            attv[k] = (h2){(half_t)pa[2 * k], (half_t)pa[2 * k + 1]};
            acc[k] = (h2){(half_t)0.f, (half_t)0.f};
        }
    }
    float M = -3.0e38f, S = 0.f;

    const int begin = rowptr[d], end = rowptr[d + 1];
    // depth-2 pipeline: cbuf = data for e, b1 = e+1, b2 = e+2 (in flight)
    uint4 cbuf[2], b1[2];
    {
        const half_t* pl = xlh + (size_t)ssrc[begin] * 64 + so;
        cbuf[0] = *reinterpret_cast<const uint4*>(pl);
        cbuf[1] = *reinterpret_cast<const uint4*>(pl + 8);
    }
    if (begin + 1 < end) {
        const half_t* pl = xlh + (size_t)ssrc[begin + 1] * 64 + so;
        b1[0] = *reinterpret_cast<const uint4*>(pl);
        b1[1] = *reinterpret_cast<const uint4*>(pl + 8);
    }
    for (int e = begin; e < end; ++e) {
        uint4 b2[2];
        const bool have2 = (e + 2 < end);
        if (have2) {
            const half_t* pl = xlh + (size_t)ssrc[e + 2] * 64 + so;
            b2[0] = *reinterpret_cast<const uint4*>(pl);
            b2[1] = *reinterpret_cast<const uint4*>(pl + 8);
        }
        const h2* cur = reinterpret_cast<const h2*>(cbuf);
        float p = 0.f;
        #pragma unroll
        for (int k = 0; k < 8; ++k) {
            h2 m = cur[k] + xrv[k];
            h2 v = __builtin_elementwise_max(m, m * c02);   // leaky_relu 0.2
            p = FDOT2(v, attv[k], p);
        }
        p += __shfl_xor(p, 1);
        p += __shfl_xor(p, 2);
        float nM = fmaxf(M, p);
        float scale = __expf(M - nM);
        float w = __expf(p - nM);
        S = fmaf(S, scale, w);
        h2 s2 = {(half_t)scale, (half_t)scale};
        h2 w2 = {(half_t)w, (half_t)w};
        #pragma unroll
        for (int k = 0; k < 8; ++k) acc[k] = acc[k] * s2 + cur[k] * w2;
        M = nM;
        // rotate pipeline
        if (e + 1 < end) { cbuf[0] = b1[0]; cbuf[1] = b1[1]; }
        if (have2)       { b1[0] = b2[0]; b1[1] = b2[1]; }
    }
    float inv = 1.f / S;
    const float* pb = bias + h * 64 + so;
    float res[16];
    #pragma unroll
    for (int k = 0; k < 8; ++k) {
        float v0 = fmaf((float)acc[k][0], inv, pb[2 * k]);
        float v1 = fmaf((float)acc[k][1], inv, pb[2 * k + 1]);
        res[2 * k]     = v0 > 0.f ? v0 : 0.f;
        res[2 * k + 1] = v1 > 0.f ? v1 : 0.f;
    }
    size_t ob = (size_t)d * HC + h * 64 + so;    // node-major output (GEMM A)
    if (OUT_F32) {
        #pragma unroll
        for (int k = 0; k < 16; k += 4) {
            float4 v = {res[k], res[k+1], res[k+2], res[k+3]};
            *reinterpret_cast<float4*>(outf + ob + k) = v;
        }
    }
    if (OUT_F16) {
        half_t o[16];
        #pragma unroll
        for (int k = 0; k < 16; ++k) o[k] = (half_t)res[k];
        const uint4* ov = reinterpret_cast<const uint4*>(o);
        *reinterpret_cast<uint4*>(outb + ob) = ov[0];
        *reinterpret_cast<uint4*>(outb + ob + 8) = ov[1];
    }
}

// ---------------- segmented pool (batch sorted) + counts ------------------
__global__ __launch_bounds__(256) void pool_kernel2(
    const float* __restrict__ h3, const int* __restrict__ batch,
    float* __restrict__ sums, float* __restrict__ counts, int N)
{
    const int wave = blockIdx.x * 4 + (threadIdx.x >> 6);
    const int lane = threadIdx.x & 63;
    const int n0 = wave * 64;
    if (n0 >= N) return;
    const int n1 = (n0 + 64 < N) ? n0 + 64 : N;
    float s = 0.f, cnt = 0.f;
    int g = batch[n0];
    for (int n = n0; n < n1; ++n) {
        int gn = batch[n];
        if (gn != g) {
            atomicAdd(&sums[g * 64 + lane], s);
            if (lane == 0) atomicAdd(&counts[g], cnt);
            s = 0.f; cnt = 0.f; g = gn;
        }
        s += h3[(size_t)n * 64 + lane];
        cnt += 1.f;
    }
    atomicAdd(&sums[g * 64 + lane], s);
    if (lane == 0) atomicAdd(&counts[g], cnt);
}

// ---------------- MLP ------------------------------------------------------
__global__ __launch_bounds__(64) void mlp_kernel(
    const float* __restrict__ sums, const float* __restrict__ counts,
    const float* __restrict__ Wm1, const float* __restrict__ bm1,
    const float* __restrict__ Wm2, const float* __restrict__ bm2,
    float* __restrict__ out)
{
    int g = blockIdx.x;
    int t = threadIdx.x;
    __shared__ float pooled[64];
    __shared__ float hidden[32];
    float cnt = counts[g];
    cnt = cnt > 1.f ? cnt : 1.f;
    pooled[t] = sums[g * 64 + t] / cnt;
    __syncthreads();
    if (t < 32) {
        float a = bm1[t];
        #pragma unroll
        for (int k = 0; k < 64; ++k) a = fmaf(pooled[k], Wm1[k * 32 + t], a);
        hidden[t] = a > 0.f ? a : 0.f;
    }
    __syncthreads();
    if (t < 2) {
        float a = bm2[t];
        #pragma unroll
        for (int j = 0; j < 32; ++j) a = fmaf(hidden[j], Wm2[j * 2 + t], a);
        out[g * 2 + t] = a;
    }
}

// ---------------- layer driver ---------------------------------------------
static void run_layer(const half_t* Xb, int K, int H,
                      const float* bl, const float* br,
                      const float* att, const float* bias_out,
                      const half_t* Wtl, const half_t* Wtr,
                      const int* rowptr, const int* ssrc, const int* dperm, int N,
                      half_t* xl, half_t* xr,
                      float* houtf, half_t* houtb,
                      hipStream_t stream)
{
    int gblocks = (N + 63) / 64;
    if (K == 128 && H == 4)
        gemm_slab<128, 4><<<gblocks, 256, 0, stream>>>(Xb, Wtl, Wtr, bl, br, xl, xr, N);
    else if (K == 256)
        gemm_slab<256, 2><<<gblocks, 256, 0, stream>>>(Xb, Wtl, Wtr, bl, br, xl, xr, N);
    else
        gemm_slab<128, 1><<<gblocks, 256, 0, stream>>>(Xb, Wtl, Wtr, bl, br, xl, xr, N);

    int ngroups = N * H;
    int blocks = (ngroups + 63) / 64;
    if (H == 4)
        gat_fused4<4, false, true><<<blocks, 256, 0, stream>>>(
            rowptr, ssrc, dperm, xl, xr, att, bias_out, houtf, houtb, N);
    else if (H == 2)
        gat_fused4<2, false, true><<<blocks, 256, 0, stream>>>(
            rowptr, ssrc, dperm, xl, xr, att, bias_out, houtf, houtb, N);
    else
        gat_fused4<1, true, false><<<blocks, 256, 0, stream>>>(
            rowptr, ssrc, dperm, xl, xr, att, bias_out, houtf, houtb, N);
}

extern "C" void kernel_launch(void* const* d_in, const int* in_sizes, int n_in,
                              void* d_out, int out_size, void* d_ws, size_t ws_size,
                              hipStream_t stream)
{
    const float* x    = (const float*)d_in[0];
    const int*   ei   = (const int*)d_in[1];
    const int*   batch= (const int*)d_in[2];
    const float* Wl1 = (const float*)d_in[3];
    const float* bl1 = (const float*)d_in[4];
    const float* Wr1 = (const float*)d_in[5];
    const float* br1 = (const float*)d_in[6];
    const float* att1= (const float*)d_in[7];
    const float* b1  = (const float*)d_in[8];
    const float* Wl2 = (const float*)d_in[9];
    const float* bl2 = (const float*)d_in[10];
    const float* Wr2 = (const float*)d_in[11];
    const float* br2 = (const float*)d_in[12];
    const float* att2= (const float*)d_in[13];
    const float* b2  = (const float*)d_in[14];
    const float* Wl3 = (const float*)d_in[15];
    const float* bl3 = (const float*)d_in[16];
    const float* Wr3 = (const float*)d_in[17];
    const float* br3 = (const float*)d_in[18];
    const float* att3= (const float*)d_in[19];
    const float* b3  = (const float*)d_in[20];
    const float* Wm1 = (const float*)d_in[21];
    const float* bm1 = (const float*)d_in[22];
    const float* Wm2 = (const float*)d_in[23];
    const float* bm2 = (const float*)d_in[24];

    const int N    = in_sizes[2];          // 50000
    const int E    = in_sizes[1] / 2;      // 800000
    const int Etot = E + N;                // + self loops
    const int K1   = in_sizes[0] / N;      // 128

    // workspace layout
    char* wsb = (char*)d_ws;
    size_t o = 0;
    auto alloc = [&](size_t bytes) { char* p = wsb + o; o += (bytes + 255) & ~(size_t)255; return p; };
    half_t* xl    = (half_t*)alloc((size_t)N * 256 * 2);
    half_t* xr    = (half_t*)alloc((size_t)N * 256 * 2);
    half_t* xb    = (half_t*)alloc((size_t)N * K1 * 2);
    half_t* h1b   = (half_t*)alloc((size_t)N * 256 * 2);
    half_t* h2b   = (half_t*)alloc((size_t)N * 128 * 2);
    float*  h3f   = (float*)alloc((size_t)N * 64 * 4);
    int*   deg    = (int*)alloc((size_t)N * 4);
    int*   rowptr = (int*)alloc((size_t)(N + 1) * 4);
    int*   cursor = (int*)alloc((size_t)N * 4);
    int*   ssrc   = (int*)alloc((size_t)Etot * 4);
    int*   dperm  = (int*)alloc((size_t)N * 4);
    int*   blockHist = (int*)alloc((size_t)SORT_BLOCKS * 256 * 4);
    int*   blockOff  = (int*)alloc((size_t)SORT_BLOCKS * 256 * 4);
    int*   blockSums = (int*)alloc((size_t)SCAN_BLOCKS * 4);
    int*   blockBase = (int*)alloc((size_t)SCAN_BLOCKS * 4);
    half_t* Wt1l = (half_t*)alloc(128 * 256 * 2);
    half_t* Wt1r = (half_t*)alloc(128 * 256 * 2);
    half_t* Wt2l = (half_t*)alloc(256 * 128 * 2);
    half_t* Wt2r = (half_t*)alloc(256 * 128 * 2);
    half_t* Wt3l = (half_t*)alloc(128 * 64 * 2);
    half_t* Wt3r = (half_t*)alloc(128 * 64 * 2);
    float* sums   = (float*)alloc(64 * 64 * 4);
    float* counts = (float*)alloc(64 * 4);
    (void)ws_size; (void)n_in; (void)out_size;

    // ---- CSR build + degree sort (shared by all 3 layers) ----
    hipMemsetAsync(deg, 0, (size_t)N * 4, stream);
    hist_kernel<<<(Etot + 255) / 256, 256, 0, stream>>>(ei, E, Etot, deg);
    scan1_kernel<<<SCAN_BLOCKS, 256, 0, stream>>>(deg, blockSums, N);
    scan2_kernel<<<1, 256, 0, stream>>>(blockSums, blockBase, rowptr, N);
    scan3_kernel<<<SCAN_BLOCKS, 256, 0, stream>>>(deg, blockBase, rowptr, cursor, N);
    scatter_kernel<<<(Etot + 255) / 256, 256, 0, stream>>>(ei, E, Etot, cursor, ssrc);
    dhist2_kernel<<<SORT_BLOCKS, 256, 0, stream>>>(rowptr, blockHist, N);
    dscan2_kernel<<<1, 256, 0, stream>>>(blockHist, blockOff);
    dscatter2_kernel<<<SORT_BLOCKS, 256, 0, stream>>>(rowptr, blockOff, dperm, N);

    // ---- convert input x + all weights to fp16 ----
    cvt_kernel<<<((N * K1) / 4 + 255) / 256, 256, 0, stream>>>(x, xb, N * K1);
    cvt_wt_all_kernel<<<(147456 + 255) / 256, 256, 0, stream>>>(
        Wl1, Wr1, Wt1l, Wt1r, Wl2, Wr2, Wt2l, Wt2r, Wl3, Wr3, Wt3l, Wt3r);

    // ---- layers ----
    run_layer(xb, K1, 4, bl1, br1, att1, b1, Wt1l, Wt1r,
              rowptr, ssrc, dperm, N, xl, xr, nullptr, h1b, stream);
    run_layer(h1b, 256, 2, bl2, br2, att2, b2, Wt2l, Wt2r,
              rowptr, ssrc, dperm, N, xl, xr, nullptr, h2b, stream);
    run_layer(h2b, 128, 1, bl3, br3, att3, b3, Wt3l, Wt3r,
              rowptr, ssrc, dperm, N, xl, xr, h3f, nullptr, stream);

    // ---- pool + MLP ----
    hipMemsetAsync(sums, 0, 64 * 64 * 4, stream);
    hipMemsetAsync(counts, 0, 64 * 4, stream);
    {
        int waves = (N + 63) / 64;
        pool_kernel2<<<(waves + 3) / 4, 256, 0, stream>>>(h3f, batch, sums, counts, N);
    }
    mlp_kernel<<<64, 64, 0, stream>>>(sums, counts, Wm1, bm1, Wm2, bm2, (float*)d_out);
}